// Round 2
// baseline (102.674 us; speedup 1.0000x reference)
//
#include <hip/hip_runtime.h>

#pragma clang fp contract(off)

#define NP 410881  // 641*641

// ---------------------------------------------------------------------------
// Fused kernel (round 5): slot tables + resize/softmax/argmax in ONE kernel.
// Round-4 post-mortem: rocprof shows the timed region is dominated by two
// ~41us harness poison fills (256 MiB each); our two kernels total ~13us.
// The separate 1-block slot_kernel + stream serialization cost ~5us of that.
// Fix: each block redundantly computes the slot reduction (probs is 68KB,
// L2-resident after the first wavefront of blocks) while its tex global
// loads are in flight (T14 issue-early/write-late split). Saves a launch,
// the inter-kernel gap, and the s_didx LDS lookup (fast path: mid = am+1).
//
// Block of 128 threads covers a 16x16 output region; each lane owns a 1x2
// x-strip inside one bilinear cell. 5x5 input texel neighborhood staged in
// LDS [cell][132]. 4 independent accumulator streams (channel c -> stream
// c&3) break the 128-deep serial max/argmax and sum-exp dependency chains.
// ---------------------------------------------------------------------------
__global__ __launch_bounds__(128) void fused_kernel(
    const float* __restrict__ logits, const float* __restrict__ probs,
    float* __restrict__ out) {
#pragma clang fp contract(off)
  __shared__ float tex[25 * 132];
  __shared__ float s_cls[128];
  __shared__ unsigned long long s_mask[2];
  int tid = threadIdx.x;
  int X0 = blockIdx.x << 4, Y0 = blockIdx.y << 4;

  // lane -> pixel pair
  int strip = tid & 7, py = tid >> 3;
  int cx = strip >> 1, h = strip & 1;
  int cy = py >> 2;
  int xa = X0 + (cx << 2) + (h << 1);
  int y = Y0 + py;

  // ---- A. issue tex global loads early; LDS writes deferred (T14) ----
  int tX = blockIdx.x << 2, tY = blockIdx.y << 2;  // texel origin
  float4 stg[7];
#pragma unroll
  for (int k = 0; k < 7; ++k) {
    int f = tid + (k << 7);
    if (f < 800) {  // 800 float4 granules = 5x5 texels x 128 ch
      int r = f / 160;
      int i = f - r * 160;
      int cc = i >> 5, c4 = i & 31;
      int gy = min(tY + r, 160);
      int gx = min(tX + cc, 160);
      stg[k] = *(const float4*)(logits + ((gy * 161 + gx) << 7) + (c4 << 2));
    }
  }

  // ---- B. slot tables, redundant per block (overlaps tex load latency) ----
  // Thread t scans probs row t, cols 0..132; strict > keeps FIRST index.
  // Two streams (even/odd cols) for ILP; exact first-index merge.
  {
    const float2* row = (const float2*)(probs + tid * 134);  // 536B: 8B-aligned
    float mA = -INFINITY, mB = -INFINITY;
    int aA = 0, aB = 1;
#pragma unroll 4
    for (int j = 0; j < 66; ++j) {
      float2 v = row[j];
      if (v.x > mA) { mA = v.x; aA = 2 * j; }
      if (v.y > mB) { mB = v.y; aB = 2 * j + 1; }
    }
    float v132 = probs[tid * 134 + 132];
    if (v132 > mA) { mA = v132; aA = 132; }
    float bv = mA;
    int bi = aA;
    if (mB > bv || (mB == bv && aB < bi)) { bv = mB; bi = aB; }
    s_cls[tid] = (float)bi;           // cls_pred[t]
    bool det = bv >= 0.7f;            // cls_conf >= CLASS_CONF_THR
    unsigned long long b = __ballot(det);
    if ((tid & 63) == 0) s_mask[tid >> 6] = b;
  }

  // ---- C. complete the LDS staging (transposed to [cell][132]) ----
#pragma unroll
  for (int k = 0; k < 7; ++k) {
    int f = tid + (k << 7);
    if (f < 800) {
      int r = f / 160;
      int i = f - r * 160;
      int cc = i >> 5, c4 = i & 31;
      *(float4*)(tex + (r * 5 + cc) * 132 + (c4 << 2)) = stg[k];
    }
  }
  __syncthreads();

  unsigned long long mlo = s_mask[0], mhi = s_mask[1];
  int ndet = __popcll(mlo) + __popcll(mhi);  // uniform

  if (ndet == 0) {  // reference zeroes everything when nothing detected
    if (y < 641) {
      if (xa < 641) {
        int i0 = y * 641 + xa;
        out[i0] = 1.0f; out[NP + i0] = 0.f; out[2 * NP + i0] = 0.f; out[3 * NP + i0] = 0.f;
      }
      if (xa + 1 < 641) {
        int i1 = y * 641 + xa + 1;
        out[i1] = 1.0f; out[NP + i1] = 0.f; out[2 * NP + i1] = 0.f; out[3 * NP + i1] = 0.f;
      }
    }
    return;
  }

  const float* p0 = tex + (cy * 5 + cx) * 132;  // a00 @ +0, a01 @ +132
  const float* p1 = p0 + 5 * 132;               // a10, a11
  float wy = 0.25f * (float)(py & 3);
  float iwy = 1.0f - wy;
  float wx0 = 0.5f * (float)h;
  float wx1 = wx0 + 0.25f;
  float iwx0 = 1.0f - wx0, iwx1 = 1.0f - wx1;

  float m0 = -INFINITY, m1 = -INFINITY;  // final masked max
  int am0 = 0, am1 = 0;                  // final masked argmax (first-index)
  float T0 = 0.f, T1 = 0.f;              // final sum exp(v) over detected
  bool dp0 = true, dp1 = true;           // detected_pixel

  if (ndet == 128) {  // fast path: masked == resized
    // 4 independent accumulator streams: stream j = channels c with c&3==j
    float ms0[4], ms1[4], Ts0[4], Ts1[4];
    int as0[4], as1[4];
#pragma unroll
    for (int j = 0; j < 4; ++j) {
      ms0[j] = -INFINITY; ms1[j] = -INFINITY;
      Ts0[j] = 0.f; Ts1[j] = 0.f;
      as0[j] = 0; as1[j] = 0;
    }
// one channel into stream J; reference op order, contract off
#define CH(A00, A01, A10, A11, CIDX, J)                                        \
  {                                                                            \
    float r0 = (A00) * iwy + (A10) * wy;                                       \
    float r1 = (A01) * iwy + (A11) * wy;                                       \
    float v0 = r0 * iwx0 + r1 * wx0;                                           \
    float v1 = r0 * iwx1 + r1 * wx1;                                           \
    bool g0 = v0 > ms0[J]; ms0[J] = g0 ? v0 : ms0[J]; as0[J] = g0 ? (CIDX) : as0[J]; \
    bool g1 = v1 > ms1[J]; ms1[J] = g1 ? v1 : ms1[J]; as1[J] = g1 ? (CIDX) : as1[J]; \
    Ts0[J] += __expf(v0);                                                      \
    Ts1[J] += __expf(v1);                                                      \
  }
#pragma unroll 2
    for (int c = 0; c < 128; c += 4) {
      float4 q00 = *(const float4*)(p0 + c);
      float4 q01 = *(const float4*)(p0 + c + 132);
      float4 q10 = *(const float4*)(p1 + c);
      float4 q11 = *(const float4*)(p1 + c + 132);
      CH(q00.x, q01.x, q10.x, q11.x, c + 0, 0);
      CH(q00.y, q01.y, q10.y, q11.y, c + 1, 1);
      CH(q00.z, q01.z, q10.z, q11.z, c + 2, 2);
      CH(q00.w, q01.w, q10.w, q11.w, c + 3, 3);
    }
#undef CH
    // exact merge: global max; on value tie, smallest channel index wins
    m0 = ms0[0]; am0 = as0[0]; m1 = ms1[0]; am1 = as1[0];
#pragma unroll
    for (int j = 1; j < 4; ++j) {
      if (ms0[j] > m0 || (ms0[j] == m0 && as0[j] < am0)) { m0 = ms0[j]; am0 = as0[j]; }
      if (ms1[j] > m1 || (ms1[j] == m1 && as1[j] < am1)) { m1 = ms1[j]; am1 = as1[j]; }
    }
    T0 = (Ts0[0] + Ts0[1]) + (Ts0[2] + Ts0[3]);
    T1 = (Ts1[0] + Ts1[1]) + (Ts1[2] + Ts1[3]);
  } else {  // general: separate raw max; per-channel detection is uniform
    float rm0 = -INFINITY, rm1 = -INFINITY;
#pragma unroll 4
    for (int c = 0; c < 128; ++c) {
      float a00 = p0[c], a01 = p0[c + 132];
      float a10 = p1[c], a11 = p1[c + 132];
      float r0 = a00 * iwy + a10 * wy;
      float r1 = a01 * iwy + a11 * wy;
      float v0 = r0 * iwx0 + r1 * wx0;
      float v1 = r0 * iwx1 + r1 * wx1;
      rm0 = fmaxf(rm0, v0);
      rm1 = fmaxf(rm1, v1);
      unsigned long long bit = (c < 64) ? (mlo >> c) : (mhi >> (c - 64));
      if (bit & 1) {  // scalar branch (wave-uniform)
        bool g0 = v0 > m0; m0 = g0 ? v0 : m0; am0 = g0 ? c : am0;
        bool g1 = v1 > m1; m1 = g1 ? v1 : m1; am1 = g1 ? c : am1;
        T0 += __expf(v0);
        T1 += __expf(v1);
      }
    }
    dp0 = (rm0 == m0);
    dp1 = (rm1 == m1);
  }

  // ---- epilogue: conf > 0.4  <=>  exp(m) > 0.4*T  (T > 0, all v bounded)
  float cg0 = ((__expf(m0) > 0.4f * T0) && dp0) ? 1.0f : 0.0f;
  float cg1 = ((__expf(m1) > 0.4f * T1) && dp1) ? 1.0f : 0.0f;
  float sem0 = s_cls[am0], sem1 = s_cls[am1];

  // mask_id_map_plus_one = inclusive-cumsum(detected)[am]
  float mid0, mid1;
  if (ndet == 128) {
    mid0 = (float)(am0 + 1);
    mid1 = (float)(am1 + 1);
  } else {
    int a = am0;
    unsigned long long ml = (a >= 63) ? mlo : (mlo & ((1ull << (a + 1)) - 1));
    int cnt = __popcll(ml);
    if (a >= 64) {
      unsigned long long mh = (a >= 127) ? mhi : (mhi & ((1ull << (a - 63)) - 1));
      cnt += __popcll(mh);
    }
    mid0 = (float)cnt;
    a = am1;
    ml = (a >= 63) ? mlo : (mlo & ((1ull << (a + 1)) - 1));
    cnt = __popcll(ml);
    if (a >= 64) {
      unsigned long long mh = (a >= 127) ? mhi : (mhi & ((1ull << (a - 63)) - 1));
      cnt += __popcll(mh);
    }
    mid1 = (float)cnt;
  }

  float th0 = (sem0 < 80.f) ? cg0 : 0.f;
  float st0 = cg0 - th0;
  float th1 = (sem1 < 80.f) ? cg1 : 0.f;
  float st1 = cg1 - th1;

  if (y < 641) {
    if (xa < 641) {
      int i0 = y * 641 + xa;
      out[i0] = mid0; out[NP + i0] = sem0; out[2 * NP + i0] = th0; out[3 * NP + i0] = st0;
    }
    if (xa + 1 < 641) {
      int i1 = y * 641 + xa + 1;
      out[i1] = mid1; out[NP + i1] = sem1; out[2 * NP + i1] = th1; out[3 * NP + i1] = st1;
    }
  }
}

extern "C" void kernel_launch(void* const* d_in, const int* in_sizes, int n_in,
                              void* d_out, int out_size, void* d_ws,
                              size_t ws_size, hipStream_t stream) {
  const float* logits = (const float*)d_in[0];  // (161,161,128) f32
  const float* probs = (const float*)d_in[1];   // (128,134) f32
  float* out = (float*)d_out;
  (void)d_ws; (void)ws_size;

  dim3 grid(41, 41);
  fused_kernel<<<grid, 128, 0, stream>>>(logits, probs, out);
}